// Round 1
// baseline (735.576 us; speedup 1.0000x reference)
//
#include <hip/hip_runtime.h>
#include <cmath>

#define HEADS 4
#define CH 64
#define HC 256          // HEADS*CH
#define NEG 0.2f

__device__ __forceinline__ float leaky(float v){ return v > 0.f ? v : NEG * v; }

// ---------------- CSR build (counting sort by dst) ----------------

__global__ void count_kernel(const int* __restrict__ ei, int E, int N, int* __restrict__ deg){
    int e = blockIdx.x * 256 + threadIdx.x;
    int ET = E + N;
    if (e >= ET) return;
    int d = (e < E) ? ei[E + e] : (e - E);   // self loop for e >= E
    atomicAdd(&deg[d], 1);
}

__global__ void scan_kernel(int* __restrict__ deg, int* __restrict__ rowptr, int N, int ET){
    __shared__ int part[1024];
    int tid = threadIdx.x;
    int chunk = (N + 1023) / 1024;
    int begin = tid * chunk; if (begin > N) begin = N;
    int stop  = begin + chunk; if (stop > N) stop = N;
    int s = 0;
    for (int i = begin; i < stop; ++i) s += deg[i];
    part[tid] = s;
    __syncthreads();
    for (int off = 1; off < 1024; off <<= 1){
        int v = (tid >= off) ? part[tid - off] : 0;
        __syncthreads();
        part[tid] += v;
        __syncthreads();
    }
    int ex = (tid == 0) ? 0 : part[tid - 1];
    for (int i = begin; i < stop; ++i){
        int c = deg[i];
        rowptr[i] = ex;
        deg[i] = ex;        // deg becomes the scatter cursor
        ex += c;
    }
    if (tid == 0) rowptr[N] = ET;
}

__global__ void scatter_kernel(const int* __restrict__ ei, int E, int N,
                               int* __restrict__ cursor, int* __restrict__ colsrc){
    int e = blockIdx.x * 256 + threadIdx.x;
    int ET = E + N;
    if (e >= ET) return;
    int s, d;
    if (e < E){ s = ei[e]; d = ei[E + e]; } else { s = d = e - E; }
    int pos = atomicAdd(&cursor[d], 1);
    colsrc[pos] = s;
}

// ---------------- node transform: h = x@W, alpha_src/dst ----------------
// 256 threads; thread tid computes output column tid (head=tid>>6, c=tid&63).

template<int FIN, int KT, int NPB>
__global__ __launch_bounds__(256) void transform_kernel(
    const float* __restrict__ xin, const float* __restrict__ W,
    const float* __restrict__ a_src, const float* __restrict__ a_dst,
    float* __restrict__ h, float* __restrict__ asrc, float* __restrict__ adst, int N)
{
    __shared__ float Wl[KT * HC];
    __shared__ float xl[NPB * FIN];
    int tid = threadIdx.x;
    int n0 = blockIdx.x * NPB;
    int nmax = N - n0; if (nmax > NPB) nmax = NPB;
    if (nmax <= 0) return;
    for (int i = tid; i < nmax * FIN; i += 256) xl[i] = xin[(size_t)n0 * FIN + i];

    float acc[NPB];
    #pragma unroll
    for (int q = 0; q < NPB; ++q) acc[q] = 0.f;

    for (int kt = 0; kt < FIN; kt += KT){
        int klen = FIN - kt; if (klen > KT) klen = KT;
        __syncthreads();
        for (int i = tid; i < klen * HC; i += 256) Wl[i] = W[(size_t)kt * HC + i];
        __syncthreads();
        for (int q = 0; q < nmax; ++q){
            float a = acc[q];
            #pragma unroll 8
            for (int k = 0; k < klen; ++k)
                a = fmaf(xl[q * FIN + kt + k], Wl[k * HC + tid], a);
            acc[q] = a;
        }
    }

    int head = tid >> 6, lane = tid & 63;
    float aw_s = a_src[tid];       // a_src[head*64 + c] == a_src[tid]
    float aw_d = a_dst[tid];
    for (int q = 0; q < nmax; ++q){
        int n = n0 + q;
        float v = acc[q];
        h[(size_t)n * HC + tid] = v;
        float ps = v * aw_s, pd = v * aw_d;
        #pragma unroll
        for (int off = 32; off > 0; off >>= 1){
            ps += __shfl_xor(ps, off);
            pd += __shfl_xor(pd, off);
        }
        if (lane == 0){ asrc[n * 4 + head] = ps; adst[n * 4 + head] = pd; }
    }
}

// ---------------- per-dst aggregation (one wave per node) ----------------
// lane = channel. Three passes over the node's in-edges: max, sum-exp, accumulate.

__global__ __launch_bounds__(256) void aggregate_kernel(
    const int* __restrict__ rowptr, const int* __restrict__ colsrc,
    const float* __restrict__ h, const float* __restrict__ asrc,
    const float* __restrict__ adst, const float* __restrict__ bias,
    float* __restrict__ hout, int N)
{
    int wv = threadIdx.x >> 6, lane = threadIdx.x & 63;
    int n = blockIdx.x * 4 + wv;
    if (n >= N) return;
    int start = rowptr[n], end = rowptr[n + 1];
    const float4 ad = *(const float4*)(adst + (size_t)n * 4);

    // pass 1: segment max (leaky applied before max, per reference)
    float m0 = -1e30f, m1 = -1e30f, m2 = -1e30f, m3 = -1e30f;
    for (int i = start + lane; i < end; i += 64){
        int s = colsrc[i];
        float4 as = *(const float4*)(asrc + (size_t)s * 4);
        m0 = fmaxf(m0, leaky(as.x + ad.x));
        m1 = fmaxf(m1, leaky(as.y + ad.y));
        m2 = fmaxf(m2, leaky(as.z + ad.z));
        m3 = fmaxf(m3, leaky(as.w + ad.w));
    }
    #pragma unroll
    for (int off = 32; off > 0; off >>= 1){
        m0 = fmaxf(m0, __shfl_xor(m0, off));
        m1 = fmaxf(m1, __shfl_xor(m1, off));
        m2 = fmaxf(m2, __shfl_xor(m2, off));
        m3 = fmaxf(m3, __shfl_xor(m3, off));
    }

    // pass 2: denom
    float d0 = 0.f, d1 = 0.f, d2 = 0.f, d3 = 0.f;
    for (int i = start + lane; i < end; i += 64){
        int s = colsrc[i];
        float4 as = *(const float4*)(asrc + (size_t)s * 4);
        d0 += __expf(leaky(as.x + ad.x) - m0);
        d1 += __expf(leaky(as.y + ad.y) - m1);
        d2 += __expf(leaky(as.z + ad.z) - m2);
        d3 += __expf(leaky(as.w + ad.w) - m3);
    }
    #pragma unroll
    for (int off = 32; off > 0; off >>= 1){
        d0 += __shfl_xor(d0, off);
        d1 += __shfl_xor(d1, off);
        d2 += __shfl_xor(d2, off);
        d3 += __shfl_xor(d3, off);
    }
    float i0 = 1.f / d0, i1 = 1.f / d1, i2 = 1.f / d2, i3 = 1.f / d3;

    // pass 3: weighted accumulate of h[src]; chunk edges by 64, shfl-broadcast weights
    float acc0 = 0.f, acc1 = 0.f, acc2 = 0.f, acc3 = 0.f;
    for (int base = start; base < end; base += 64){
        int cnt = end - base; if (cnt > 64) cnt = 64;
        float w0 = 0.f, w1 = 0.f, w2 = 0.f, w3 = 0.f; int sm = 0;
        if (lane < cnt){
            int s = colsrc[base + lane];
            sm = s;
            float4 as = *(const float4*)(asrc + (size_t)s * 4);
            w0 = __expf(leaky(as.x + ad.x) - m0) * i0;
            w1 = __expf(leaky(as.y + ad.y) - m1) * i1;
            w2 = __expf(leaky(as.z + ad.z) - m2) * i2;
            w3 = __expf(leaky(as.w + ad.w) - m3) * i3;
        }
        for (int j = 0; j < cnt; ++j){
            int s = __shfl(sm, j);
            float a0 = __shfl(w0, j), a1 = __shfl(w1, j);
            float a2 = __shfl(w2, j), a3 = __shfl(w3, j);
            const float* hs = h + (size_t)s * HC;
            acc0 = fmaf(a0, hs[lane],       acc0);
            acc1 = fmaf(a1, hs[64 + lane],  acc1);
            acc2 = fmaf(a2, hs[128 + lane], acc2);
            acc3 = fmaf(a3, hs[192 + lane], acc3);
        }
    }
    float o = (acc0 + acc1 + acc2 + acc3) * 0.25f + bias[lane];
    hout[(size_t)n * CH + lane] = (o > 0.f) ? o : expm1f(o);   // ELU
}

// ---------------- scorer MLP ----------------
// one thread per node; Ws1 (96x64) in LDS; donor part folded into d1 once per block.

__global__ __launch_bounds__(256) void scorer_kernel(
    const float* __restrict__ h2, const float* __restrict__ donor,
    const float* __restrict__ Ws1, const float* __restrict__ bs1,
    const float* __restrict__ Ws2, const float* __restrict__ bs2,
    float* __restrict__ out, int N)
{
    __shared__ float Wl[96 * 64];
    __shared__ float d1[64];
    __shared__ float w2l[64];
    int tid = threadIdx.x;
    for (int i = tid; i < 96 * 64; i += 256) Wl[i] = Ws1[i];
    __syncthreads();
    if (tid < 64){
        float s = bs1[tid];
        for (int k = 0; k < 32; ++k) s = fmaf(donor[k], Wl[(64 + k) * 64 + tid], s);
        d1[tid] = s;
        w2l[tid] = Ws2[tid];
    }
    __syncthreads();
    int n = blockIdx.x * 256 + tid;
    if (n >= N) return;

    float hrow[64];
    const float4* hp = (const float4*)(h2 + (size_t)n * 64);
    #pragma unroll
    for (int i = 0; i < 16; ++i){
        float4 v = hp[i];
        hrow[4*i] = v.x; hrow[4*i+1] = v.y; hrow[4*i+2] = v.z; hrow[4*i+3] = v.w;
    }
    float logit = bs2[0];
    for (int j = 0; j < 64; ++j){
        float s = d1[j];
        #pragma unroll
        for (int k = 0; k < 64; ++k) s = fmaf(hrow[k], Wl[k * 64 + j], s);
        logit = fmaf(fmaxf(s, 0.f), w2l[j], logit);
    }
    out[n] = logit;
}

// ---------------- launch ----------------

extern "C" void kernel_launch(void* const* d_in, const int* in_sizes, int n_in,
                              void* d_out, int out_size, void* d_ws, size_t ws_size,
                              hipStream_t stream)
{
    const float* x    = (const float*)d_in[0];
    const int*   ei   = (const int*)  d_in[1];
    const float* donor= (const float*)d_in[2];
    const float* W1   = (const float*)d_in[3];
    const float* as1  = (const float*)d_in[4];
    const float* ad1  = (const float*)d_in[5];
    const float* b1   = (const float*)d_in[6];
    const float* W2   = (const float*)d_in[7];
    const float* as2  = (const float*)d_in[8];
    const float* ad2  = (const float*)d_in[9];
    const float* b2   = (const float*)d_in[10];
    const float* Ws1  = (const float*)d_in[11];
    const float* bs1  = (const float*)d_in[12];
    const float* Ws2  = (const float*)d_in[13];
    const float* bs2  = (const float*)d_in[14];

    const int N  = in_sizes[0] / 27;    // 50000
    const int E  = in_sizes[1] / 2;     // 800000
    const int ET = E + N;               // with self loops

    char* ws = (char*)d_ws;
    auto alloc = [&](size_t bytes) -> void* {
        void* p = (void*)ws;
        ws += (bytes + 255) / 256 * 256;
        return p;
    };
    int*   rowptr = (int*)  alloc((size_t)(N + 1) * 4);
    int*   deg    = (int*)  alloc((size_t)N * 4);          // counts -> cursor
    int*   colsrc = (int*)  alloc((size_t)ET * 4);
    float* hbig   = (float*)alloc((size_t)N * HC * 4);     // [N,256]
    float* asrc   = (float*)alloc((size_t)N * 4 * 4);
    float* adst   = (float*)alloc((size_t)N * 4 * 4);
    float* hmid   = (float*)alloc((size_t)N * CH * 4);     // [N,64] layer output

    // --- CSR build ---
    hipMemsetAsync(deg, 0, (size_t)N * 4, stream);
    count_kernel<<<(ET + 255) / 256, 256, 0, stream>>>(ei, E, N, deg);
    scan_kernel<<<1, 1024, 0, stream>>>(deg, rowptr, N, ET);
    scatter_kernel<<<(ET + 255) / 256, 256, 0, stream>>>(ei, E, N, deg, colsrc);

    // --- layer 1 ---
    transform_kernel<27, 27, 16><<<(N + 15) / 16, 256, 0, stream>>>(
        x, W1, as1, ad1, hbig, asrc, adst, N);
    aggregate_kernel<<<(N + 3) / 4, 256, 0, stream>>>(
        rowptr, colsrc, hbig, asrc, adst, b1, hmid, N);

    // --- layer 2 (reads hmid, reuses hbig/asrc/adst, writes back into hmid) ---
    transform_kernel<64, 32, 16><<<(N + 15) / 16, 256, 0, stream>>>(
        hmid, W2, as2, ad2, hbig, asrc, adst, N);
    aggregate_kernel<<<(N + 3) / 4, 256, 0, stream>>>(
        rowptr, colsrc, hbig, asrc, adst, b2, hmid, N);

    // --- scorer ---
    scorer_kernel<<<(N + 255) / 256, 256, 0, stream>>>(
        hmid, donor, Ws1, bs1, Ws2, bs2, (float*)d_out, N);
}

// Round 2
// 563.173 us; speedup vs baseline: 1.3061x; 1.3061x over previous
//
#include <hip/hip_runtime.h>
#include <hip/hip_fp16.h>
#include <cmath>

#define HEADS 4
#define CH 64
#define HC 256
#define NEG 0.2f

typedef __attribute__((ext_vector_type(8))) short short8;
typedef __attribute__((ext_vector_type(4))) float f32x4;

__device__ __forceinline__ float leaky(float v){ return v > 0.f ? v : NEG * v; }

__device__ __forceinline__ short bf16_rne(float f){
    unsigned u = __float_as_uint(f);
    unsigned r = u + 0x7fffu + ((u >> 16) & 1u);
    return (short)(r >> 16);
}
__device__ __forceinline__ float bf16_to_f(short s){
    return __uint_as_float(((unsigned)(unsigned short)s) << 16);
}

// ---------------- CSR build (counting sort by dst) ----------------

__global__ void count_kernel(const int* __restrict__ ei, int E, int N, int* __restrict__ deg){
    int e = blockIdx.x * 256 + threadIdx.x;
    int ET = E + N;
    if (e >= ET) return;
    int d = (e < E) ? ei[E + e] : (e - E);
    atomicAdd(&deg[d], 1);
}

__global__ void scan_kernel(int* __restrict__ deg, int* __restrict__ rowptr, int N, int ET){
    __shared__ int part[1024];
    int tid = threadIdx.x;
    int chunk = (N + 1023) / 1024;
    int begin = tid * chunk; if (begin > N) begin = N;
    int stop  = begin + chunk; if (stop > N) stop = N;
    int s = 0;
    for (int i = begin; i < stop; ++i) s += deg[i];
    part[tid] = s;
    __syncthreads();
    for (int off = 1; off < 1024; off <<= 1){
        int v = (tid >= off) ? part[tid - off] : 0;
        __syncthreads();
        part[tid] += v;
        __syncthreads();
    }
    int ex = (tid == 0) ? 0 : part[tid - 1];
    for (int i = begin; i < stop; ++i){
        int c = deg[i];
        rowptr[i] = ex;
        deg[i] = ex;
        ex += c;
    }
    if (tid == 0) rowptr[N] = ET;
}

__global__ void scatter_kernel(const int* __restrict__ ei, int E, int N,
                               int* __restrict__ cursor, int* __restrict__ colsrc){
    int e = blockIdx.x * 256 + threadIdx.x;
    int ET = E + N;
    if (e >= ET) return;
    int s, d;
    if (e < E){ s = ei[e]; d = ei[E + e]; } else { s = d = e - E; }
    int pos = atomicAdd(&cursor[d], 1);
    colsrc[pos] = s;
}

// ---------------- MFMA node transform ----------------
// Block: 256 threads = 4 waves, 64 nodes (16/wave), NT*16 output cols at offset c0.
// h = x @ W via bf16x3 split (hi*hi + lo*hi + hi*lo) -> ~fp32 accuracy.
// A-frag: A[m=lane&15][k=quad*8+j]; B-frag: B[n=lane&15][k=quad*8+j] (W stored transposed);
// C/D: col=lane&15, row=quad*4+reg.

template<int FIN, int KSTEPS, int NT>
__global__ __launch_bounds__(256) void transform_mfma(
    const float* __restrict__ xin, const float* __restrict__ W,
    const float* __restrict__ a_src, const float* __restrict__ a_dst,
    __half* __restrict__ h, float* __restrict__ asrc, float* __restrict__ adst,
    int N)
{
    constexpr int KP = KSTEPS * 32;     // K span (padded to 32-mult)
    constexpr int XP = KP + 4;          // xl pitch (floats): 16B-aligned, odd-ish banks
    constexpr int WP = KP + 8;          // wt pitch (shorts): 16B-aligned rows
    __shared__ float xl[64 * XP];
    __shared__ short wt_hi[NT * 16 * WP];
    __shared__ short wt_lo[NT * 16 * WP];

    const int tid = threadIdx.x;
    const int n0 = blockIdx.x * 64;
    const int c0 = blockIdx.y * (NT * 16);

    // stage x rows (pad K with zeros)
    if (FIN == 64) {
        for (int t = tid; t < 64 * 16; t += 256) {
            int row = t >> 4, c4 = (t & 15) * 4;
            int n = n0 + row;
            float4 v = make_float4(0.f, 0.f, 0.f, 0.f);
            if (n < N) v = *(const float4*)(xin + (size_t)n * 64 + c4);
            *(float4*)(xl + row * XP + c4) = v;
        }
    } else {
        for (int t = tid; t < 64 * KP; t += 256) {
            int row = t / KP, k = t % KP;
            int n = n0 + row;
            float v = 0.f;
            if (n < N && k < FIN) v = xin[(size_t)n * FIN + k];
            xl[row * XP + k] = v;
        }
    }
    // stage W transposed [n][k], split into bf16 hi/lo
    for (int t = tid; t < NT * 16 * KP; t += 256) {
        int n = t / KP, k = t % KP;
        float v = (k < FIN) ? W[(size_t)k * HC + c0 + n] : 0.f;
        short hi = bf16_rne(v);
        wt_hi[n * WP + k] = hi;
        wt_lo[n * WP + k] = bf16_rne(v - bf16_to_f(hi));
    }
    __syncthreads();

    const int wv = tid >> 6, lane = tid & 63;
    const int quad = lane >> 4, ln = lane & 15;
    const int myrow = wv * 16 + ln;

    f32x4 acc[NT];
    #pragma unroll
    for (int i = 0; i < NT; ++i) acc[i] = (f32x4){0.f, 0.f, 0.f, 0.f};

    #pragma unroll
    for (int ks = 0; ks < KSTEPS; ++ks) {
        const int k0 = ks * 32 + quad * 8;
        const float* ap = xl + myrow * XP + k0;
        float4 f0 = *(const float4*)ap;
        float4 f1 = *(const float4*)(ap + 4);
        float fa[8] = {f0.x, f0.y, f0.z, f0.w, f1.x, f1.y, f1.z, f1.w};
        short8 ahi, alo;
        #pragma unroll
        for (int e = 0; e < 8; ++e) {
            short hi = bf16_rne(fa[e]);
            ahi[e] = hi;
            alo[e] = bf16_rne(fa[e] - bf16_to_f(hi));
        }
        #pragma unroll
        for (int nt = 0; nt < NT; ++nt) {
            short8 bhi = *(const short8*)(wt_hi + (nt * 16 + ln) * WP + k0);
            short8 blo = *(const short8*)(wt_lo + (nt * 16 + ln) * WP + k0);
            acc[nt] = __builtin_amdgcn_mfma_f32_16x16x32_bf16(ahi, bhi, acc[nt], 0, 0, 0);
            acc[nt] = __builtin_amdgcn_mfma_f32_16x16x32_bf16(alo, bhi, acc[nt], 0, 0, 0);
            acc[nt] = __builtin_amdgcn_mfma_f32_16x16x32_bf16(ahi, blo, acc[nt], 0, 0, 0);
        }
    }

    // write h (fp16) : lane holds C[row=quad*4+r][col=nt*16+ln]
    #pragma unroll
    for (int r = 0; r < 4; ++r) {
        int n = n0 + wv * 16 + quad * 4 + r;
        if (n < N) {
            #pragma unroll
            for (int nt = 0; nt < NT; ++nt)
                h[(size_t)n * HC + c0 + nt * 16 + ln] = __float2half(acc[nt][r]);
        }
    }

    // alpha_src/dst from fp32 accumulators (per head = 4 consecutive ntiles)
    float aS[NT], aD[NT];
    #pragma unroll
    for (int nt = 0; nt < NT; ++nt) {
        aS[nt] = a_src[c0 + nt * 16 + ln];
        aD[nt] = a_dst[c0 + nt * 16 + ln];
    }
    #pragma unroll
    for (int hl = 0; hl < NT / 4; ++hl) {
        #pragma unroll
        for (int r = 0; r < 4; ++r) {
            float ps = 0.f, pd = 0.f;
            #pragma unroll
            for (int i = 0; i < 4; ++i) {
                ps = fmaf(acc[hl * 4 + i][r], aS[hl * 4 + i], ps);
                pd = fmaf(acc[hl * 4 + i][r], aD[hl * 4 + i], pd);
            }
            #pragma unroll
            for (int off = 1; off < 16; off <<= 1) {
                ps += __shfl_xor(ps, off);
                pd += __shfl_xor(pd, off);
            }
            if (ln == 0) {
                int n = n0 + wv * 16 + quad * 4 + r;
                if (n < N) {
                    int hg = c0 / 64 + hl;
                    asrc[n * 4 + hg] = ps;
                    adst[n * 4 + hg] = pd;
                }
            }
        }
    }
}

// ---------------- per-dst aggregation (one wave per node) ----------------
// Fused online softmax (single sweep) + fp16 h gather.

__global__ __launch_bounds__(256) void aggregate_kernel(
    const int* __restrict__ rowptr, const int* __restrict__ colsrc,
    const __half* __restrict__ h, const float* __restrict__ asrc,
    const float* __restrict__ adst, const float* __restrict__ bias,
    float* __restrict__ hout, int N)
{
    int wv = threadIdx.x >> 6, lane = threadIdx.x & 63;
    int n = blockIdx.x * 4 + wv;
    if (n >= N) return;
    int start = rowptr[n], end = rowptr[n + 1];
    const float4 ad = *(const float4*)(adst + (size_t)n * 4);

    // online max + rescaled sum, one pass
    float m0 = -1e30f, m1 = -1e30f, m2 = -1e30f, m3 = -1e30f;
    float s0 = 0.f, s1 = 0.f, s2 = 0.f, s3 = 0.f;
    for (int i = start + lane; i < end; i += 64){
        int s = colsrc[i];
        float4 as = *(const float4*)(asrc + (size_t)s * 4);
        float e, nm;
        e = leaky(as.x + ad.x); nm = fmaxf(m0, e); s0 = s0 * __expf(m0 - nm) + __expf(e - nm); m0 = nm;
        e = leaky(as.y + ad.y); nm = fmaxf(m1, e); s1 = s1 * __expf(m1 - nm) + __expf(e - nm); m1 = nm;
        e = leaky(as.z + ad.z); nm = fmaxf(m2, e); s2 = s2 * __expf(m2 - nm) + __expf(e - nm); m2 = nm;
        e = leaky(as.w + ad.w); nm = fmaxf(m3, e); s3 = s3 * __expf(m3 - nm) + __expf(e - nm); m3 = nm;
    }
    #pragma unroll
    for (int off = 1; off < 64; off <<= 1){
        float om, os, nm;
        om = __shfl_xor(m0, off); os = __shfl_xor(s0, off);
        nm = fmaxf(m0, om); s0 = s0 * __expf(m0 - nm) + os * __expf(om - nm); m0 = nm;
        om = __shfl_xor(m1, off); os = __shfl_xor(s1, off);
        nm = fmaxf(m1, om); s1 = s1 * __expf(m1 - nm) + os * __expf(om - nm); m1 = nm;
        om = __shfl_xor(m2, off); os = __shfl_xor(s2, off);
        nm = fmaxf(m2, om); s2 = s2 * __expf(m2 - nm) + os * __expf(om - nm); m2 = nm;
        om = __shfl_xor(m3, off); os = __shfl_xor(s3, off);
        nm = fmaxf(m3, om); s3 = s3 * __expf(m3 - nm) + os * __expf(om - nm); m3 = nm;
    }
    float i0 = 1.f / s0, i1 = 1.f / s1, i2 = 1.f / s2, i3 = 1.f / s3;

    // weighted accumulate of h[src] (fp16), shfl-broadcast weights
    float acc0 = 0.f, acc1 = 0.f, acc2 = 0.f, acc3 = 0.f;
    for (int base = start; base < end; base += 64){
        int cnt = end - base; if (cnt > 64) cnt = 64;
        float w0 = 0.f, w1 = 0.f, w2 = 0.f, w3 = 0.f; int sm = 0;
        if (lane < cnt){
            int s = colsrc[base + lane];
            sm = s;
            float4 as = *(const float4*)(asrc + (size_t)s * 4);
            w0 = __expf(leaky(as.x + ad.x) - m0) * i0;
            w1 = __expf(leaky(as.y + ad.y) - m1) * i1;
            w2 = __expf(leaky(as.z + ad.z) - m2) * i2;
            w3 = __expf(leaky(as.w + ad.w) - m3) * i3;
        }
        for (int j = 0; j < cnt; ++j){
            int s = __shfl(sm, j);
            float a0 = __shfl(w0, j), a1 = __shfl(w1, j);
            float a2 = __shfl(w2, j), a3 = __shfl(w3, j);
            const __half* hs = h + (size_t)s * HC;
            acc0 = fmaf(a0, __half2float(hs[lane]),       acc0);
            acc1 = fmaf(a1, __half2float(hs[64 + lane]),  acc1);
            acc2 = fmaf(a2, __half2float(hs[128 + lane]), acc2);
            acc3 = fmaf(a3, __half2float(hs[192 + lane]), acc3);
        }
    }
    float o = (acc0 + acc1 + acc2 + acc3) * 0.25f + bias[lane];
    hout[(size_t)n * CH + lane] = (o > 0.f) ? o : expm1f(o);
}

// ---------------- scorer MLP ----------------

__global__ __launch_bounds__(256) void scorer_kernel(
    const float* __restrict__ h2, const float* __restrict__ donor,
    const float* __restrict__ Ws1, const float* __restrict__ bs1,
    const float* __restrict__ Ws2, const float* __restrict__ bs2,
    float* __restrict__ out, int N)
{
    __shared__ float Wl[96 * 64];
    __shared__ float d1[64];
    __shared__ float w2l[64];
    int tid = threadIdx.x;
    for (int i = tid; i < 96 * 64; i += 256) Wl[i] = Ws1[i];
    __syncthreads();
    if (tid < 64){
        float s = bs1[tid];
        for (int k = 0; k < 32; ++k) s = fmaf(donor[k], Wl[(64 + k) * 64 + tid], s);
        d1[tid] = s;
        w2l[tid] = Ws2[tid];
    }
    __syncthreads();
    int n = blockIdx.x * 256 + tid;
    if (n >= N) return;

    float hrow[64];
    const float4* hp = (const float4*)(h2 + (size_t)n * 64);
    #pragma unroll
    for (int i = 0; i < 16; ++i){
        float4 v = hp[i];
        hrow[4*i] = v.x; hrow[4*i+1] = v.y; hrow[4*i+2] = v.z; hrow[4*i+3] = v.w;
    }
    float logit = bs2[0];
    for (int j = 0; j < 64; ++j){
        float s = d1[j];
        #pragma unroll
        for (int k = 0; k < 64; ++k) s = fmaf(hrow[k], Wl[k * 64 + j], s);
        logit = fmaf(fmaxf(s, 0.f), w2l[j], logit);
    }
    out[n] = logit;
}

// ---------------- launch ----------------

extern "C" void kernel_launch(void* const* d_in, const int* in_sizes, int n_in,
                              void* d_out, int out_size, void* d_ws, size_t ws_size,
                              hipStream_t stream)
{
    const float* x    = (const float*)d_in[0];
    const int*   ei   = (const int*)  d_in[1];
    const float* donor= (const float*)d_in[2];
    const float* W1   = (const float*)d_in[3];
    const float* as1  = (const float*)d_in[4];
    const float* ad1  = (const float*)d_in[5];
    const float* b1   = (const float*)d_in[6];
    const float* W2   = (const float*)d_in[7];
    const float* as2  = (const float*)d_in[8];
    const float* ad2  = (const float*)d_in[9];
    const float* b2   = (const float*)d_in[10];
    const float* Ws1  = (const float*)d_in[11];
    const float* bs1  = (const float*)d_in[12];
    const float* Ws2  = (const float*)d_in[13];
    const float* bs2  = (const float*)d_in[14];

    const int N  = in_sizes[0] / 27;
    const int E  = in_sizes[1] / 2;
    const int ET = E + N;

    char* ws = (char*)d_ws;
    auto alloc = [&](size_t bytes) -> void* {
        void* p = (void*)ws;
        ws += (bytes + 255) / 256 * 256;
        return p;
    };
    int*    rowptr = (int*)   alloc((size_t)(N + 1) * 4);
    int*    deg    = (int*)   alloc((size_t)N * 4);
    int*    colsrc = (int*)   alloc((size_t)ET * 4);
    __half* hbig   = (__half*)alloc((size_t)N * HC * 2);   // fp16 gather table
    float*  asrc   = (float*) alloc((size_t)N * 4 * 4);
    float*  adst   = (float*) alloc((size_t)N * 4 * 4);
    float*  hmid   = (float*) alloc((size_t)N * CH * 4);

    // CSR build
    hipMemsetAsync(deg, 0, (size_t)N * 4, stream);
    count_kernel<<<(ET + 255) / 256, 256, 0, stream>>>(ei, E, N, deg);
    scan_kernel<<<1, 1024, 0, stream>>>(deg, rowptr, N, ET);
    scatter_kernel<<<(ET + 255) / 256, 256, 0, stream>>>(ei, E, N, deg, colsrc);

    const int nblk = (N + 63) / 64;

    // layer 1: FIN=27 (K padded to 32), all 256 cols per block
    transform_mfma<27, 1, 16><<<dim3(nblk, 1), 256, 0, stream>>>(
        x, W1, as1, ad1, hbig, asrc, adst, N);
    aggregate_kernel<<<(N + 3) / 4, 256, 0, stream>>>(
        rowptr, colsrc, hbig, asrc, adst, b1, hmid, N);

    // layer 2: FIN=64 (2 k-steps), 128 cols per block (y-split)
    transform_mfma<64, 2, 8><<<dim3(nblk, 2), 256, 0, stream>>>(
        hmid, W2, as2, ad2, hbig, asrc, adst, N);
    aggregate_kernel<<<(N + 3) / 4, 256, 0, stream>>>(
        rowptr, colsrc, hbig, asrc, adst, b2, hmid, N);

    // scorer
    scorer_kernel<<<(N + 255) / 256, 256, 0, stream>>>(
        hmid, donor, Ws1, bs1, Ws2, bs2, (float*)d_out, N);
}

// Round 3
// 459.551 us; speedup vs baseline: 1.6006x; 1.2255x over previous
//
#include <hip/hip_runtime.h>
#include <hip/hip_fp16.h>
#include <cmath>

#define HEADS 4
#define CH 64
#define HC 256
#define NEG 0.2f
#define SCAN_TILE 2048

typedef __attribute__((ext_vector_type(8))) short short8;
typedef __attribute__((ext_vector_type(4))) float f32x4;

__device__ __forceinline__ float leaky(float v){ return v > 0.f ? v : NEG * v; }

__device__ __forceinline__ short bf16_rne(float f){
    unsigned u = __float_as_uint(f);
    unsigned r = u + 0x7fffu + ((u >> 16) & 1u);
    return (short)(r >> 16);
}
__device__ __forceinline__ float bf16_to_f(short s){
    return __uint_as_float(((unsigned)(unsigned short)s) << 16);
}

// ---------------- CSR build (counting sort by dst) ----------------

__global__ void count_kernel(const int* __restrict__ ei, int E, int N, int* __restrict__ deg){
    int e = blockIdx.x * 256 + threadIdx.x;
    int ET = E + N;
    if (e >= ET) return;
    int d = (e < E) ? ei[E + e] : (e - E);
    atomicAdd(&deg[d], 1);
}

// hierarchical exclusive scan of deg[0..N) -> rowptr, cursor
__global__ void blocksum_kernel(const int* __restrict__ deg, int N, int* __restrict__ bsum){
    __shared__ int wsum[4];
    int tid = threadIdx.x;
    int base = blockIdx.x * SCAN_TILE;
    int s = 0;
    for (int i = tid; i < SCAN_TILE; i += 256){
        int idx = base + i;
        s += (idx < N) ? deg[idx] : 0;
    }
    #pragma unroll
    for (int off = 32; off > 0; off >>= 1) s += __shfl_down(s, off);
    if ((tid & 63) == 0) wsum[tid >> 6] = s;
    __syncthreads();
    if (tid == 0) bsum[blockIdx.x] = wsum[0] + wsum[1] + wsum[2] + wsum[3];
}

__global__ void scan_bsum_kernel(int* __restrict__ bsum, int B, int* __restrict__ rowptr, int N, int ET){
    if (threadIdx.x == 0){
        int acc = 0;
        for (int i = 0; i < B; ++i){ int c = bsum[i]; bsum[i] = acc; acc += c; }
        rowptr[N] = ET;
    }
}

__global__ void scan_write_kernel(const int* __restrict__ deg, const int* __restrict__ bsum,
                                  int N, int* __restrict__ rowptr, int* __restrict__ cursor){
    __shared__ int wsum[4];
    int tid = threadIdx.x;
    int base = blockIdx.x * SCAN_TILE + tid * 8;
    int v[8]; int s = 0;
    #pragma unroll
    for (int j = 0; j < 8; ++j){
        int idx = base + j;
        v[j] = (idx < N) ? deg[idx] : 0;
        s += v[j];
    }
    int lane = tid & 63, wv = tid >> 6;
    int incl = s;
    #pragma unroll
    for (int off = 1; off < 64; off <<= 1){
        int t = __shfl_up(incl, off);
        if (lane >= off) incl += t;
    }
    if (lane == 63) wsum[wv] = incl;
    __syncthreads();
    int excl = incl - s + bsum[blockIdx.x];
    for (int w = 0; w < wv; ++w) excl += wsum[w];
    #pragma unroll
    for (int j = 0; j < 8; ++j){
        int idx = base + j;
        if (idx < N){ rowptr[idx] = excl; cursor[idx] = excl; excl += v[j]; }
    }
}

__global__ void scatter_kernel(const int* __restrict__ ei, int E, int N,
                               int* __restrict__ cursor, int* __restrict__ colsrc){
    int e = blockIdx.x * 256 + threadIdx.x;
    int ET = E + N;
    if (e >= ET) return;
    int s, d;
    if (e < E){ s = ei[e]; d = ei[E + e]; } else { s = d = e - E; }
    int pos = atomicAdd(&cursor[d], 1);
    colsrc[pos] = s;
}

// ---------------- MFMA node transform ----------------
// Block: 256 threads = 4 waves, 64 nodes (16/wave), NT*16 output cols at offset c0.
// h = x @ W via bf16x3 split -> ~fp32 accuracy.
// A-frag: A[m=lane&15][k=quad*8+j]; B-frag: B[n=lane&15][k=quad*8+j] (W transposed in LDS);
// C/D: col=lane&15, row=quad*4+reg.

template<int FIN, int KSTEPS, int NT>
__global__ __launch_bounds__(256) void transform_mfma(
    const float* __restrict__ xin, const float* __restrict__ W,
    const float* __restrict__ a_src, const float* __restrict__ a_dst,
    __half* __restrict__ h, float* __restrict__ asrc, float* __restrict__ adst,
    int N)
{
    constexpr int KP = KSTEPS * 32;
    constexpr int XP = KP + 4;
    constexpr int WP = KP + 8;
    __shared__ float xl[64 * XP];
    __shared__ short wt_hi[NT * 16 * WP];
    __shared__ short wt_lo[NT * 16 * WP];

    const int tid = threadIdx.x;
    const int n0 = blockIdx.x * 64;
    const int c0 = blockIdx.y * (NT * 16);

    if (FIN == 64) {
        for (int t = tid; t < 64 * 16; t += 256) {
            int row = t >> 4, c4 = (t & 15) * 4;
            int n = n0 + row;
            float4 v = make_float4(0.f, 0.f, 0.f, 0.f);
            if (n < N) v = *(const float4*)(xin + (size_t)n * 64 + c4);
            *(float4*)(xl + row * XP + c4) = v;
        }
    } else {
        for (int t = tid; t < 64 * KP; t += 256) {
            int row = t / KP, k = t % KP;
            int n = n0 + row;
            float v = 0.f;
            if (n < N && k < FIN) v = xin[(size_t)n * FIN + k];
            xl[row * XP + k] = v;
        }
    }
    for (int t = tid; t < NT * 16 * KP; t += 256) {
        int n = t / KP, k = t % KP;
        float v = (k < FIN) ? W[(size_t)k * HC + c0 + n] : 0.f;
        short hi = bf16_rne(v);
        wt_hi[n * WP + k] = hi;
        wt_lo[n * WP + k] = bf16_rne(v - bf16_to_f(hi));
    }
    __syncthreads();

    const int wv = tid >> 6, lane = tid & 63;
    const int quad = lane >> 4, ln = lane & 15;
    const int myrow = wv * 16 + ln;

    f32x4 acc[NT];
    #pragma unroll
    for (int i = 0; i < NT; ++i) acc[i] = (f32x4){0.f, 0.f, 0.f, 0.f};

    #pragma unroll
    for (int ks = 0; ks < KSTEPS; ++ks) {
        const int k0 = ks * 32 + quad * 8;
        const float* ap = xl + myrow * XP + k0;
        float4 f0 = *(const float4*)ap;
        float4 f1 = *(const float4*)(ap + 4);
        float fa[8] = {f0.x, f0.y, f0.z, f0.w, f1.x, f1.y, f1.z, f1.w};
        short8 ahi, alo;
        #pragma unroll
        for (int e = 0; e < 8; ++e) {
            short hi = bf16_rne(fa[e]);
            ahi[e] = hi;
            alo[e] = bf16_rne(fa[e] - bf16_to_f(hi));
        }
        #pragma unroll
        for (int nt = 0; nt < NT; ++nt) {
            short8 bhi = *(const short8*)(wt_hi + (nt * 16 + ln) * WP + k0);
            short8 blo = *(const short8*)(wt_lo + (nt * 16 + ln) * WP + k0);
            acc[nt] = __builtin_amdgcn_mfma_f32_16x16x32_bf16(ahi, bhi, acc[nt], 0, 0, 0);
            acc[nt] = __builtin_amdgcn_mfma_f32_16x16x32_bf16(alo, bhi, acc[nt], 0, 0, 0);
            acc[nt] = __builtin_amdgcn_mfma_f32_16x16x32_bf16(ahi, blo, acc[nt], 0, 0, 0);
        }
    }

    #pragma unroll
    for (int r = 0; r < 4; ++r) {
        int n = n0 + wv * 16 + quad * 4 + r;
        if (n < N) {
            #pragma unroll
            for (int nt = 0; nt < NT; ++nt)
                h[(size_t)n * HC + c0 + nt * 16 + ln] = __float2half(acc[nt][r]);
        }
    }

    float aS[NT], aD[NT];
    #pragma unroll
    for (int nt = 0; nt < NT; ++nt) {
        aS[nt] = a_src[c0 + nt * 16 + ln];
        aD[nt] = a_dst[c0 + nt * 16 + ln];
    }
    #pragma unroll
    for (int hl = 0; hl < NT / 4; ++hl) {
        #pragma unroll
        for (int r = 0; r < 4; ++r) {
            float ps = 0.f, pd = 0.f;
            #pragma unroll
            for (int i = 0; i < 4; ++i) {
                ps = fmaf(acc[hl * 4 + i][r], aS[hl * 4 + i], ps);
                pd = fmaf(acc[hl * 4 + i][r], aD[hl * 4 + i], pd);
            }
            #pragma unroll
            for (int off = 1; off < 16; off <<= 1) {
                ps += __shfl_xor(ps, off);
                pd += __shfl_xor(pd, off);
            }
            if (ln == 0) {
                int n = n0 + wv * 16 + quad * 4 + r;
                if (n < N) {
                    int hg = c0 / 64 + hl;
                    asrc[n * 4 + hg] = ps;
                    adst[n * 4 + hg] = pd;
                }
            }
        }
    }
}

// ---------------- per-dst aggregation (one wave per node) ----------------

__global__ __launch_bounds__(256) void aggregate_kernel(
    const int* __restrict__ rowptr, const int* __restrict__ colsrc,
    const __half* __restrict__ h, const float* __restrict__ asrc,
    const float* __restrict__ adst, const float* __restrict__ bias,
    float* __restrict__ hout, int N)
{
    int wv = threadIdx.x >> 6, lane = threadIdx.x & 63;
    int n = blockIdx.x * 4 + wv;
    if (n >= N) return;
    int start = rowptr[n], end = rowptr[n + 1];
    const float4 ad = *(const float4*)(adst + (size_t)n * 4);

    float m0 = -1e30f, m1 = -1e30f, m2 = -1e30f, m3 = -1e30f;
    float s0 = 0.f, s1 = 0.f, s2 = 0.f, s3 = 0.f;
    for (int i = start + lane; i < end; i += 64){
        int s = colsrc[i];
        float4 as = *(const float4*)(asrc + (size_t)s * 4);
        float e, nm;
        e = leaky(as.x + ad.x); nm = fmaxf(m0, e); s0 = s0 * __expf(m0 - nm) + __expf(e - nm); m0 = nm;
        e = leaky(as.y + ad.y); nm = fmaxf(m1, e); s1 = s1 * __expf(m1 - nm) + __expf(e - nm); m1 = nm;
        e = leaky(as.z + ad.z); nm = fmaxf(m2, e); s2 = s2 * __expf(m2 - nm) + __expf(e - nm); m2 = nm;
        e = leaky(as.w + ad.w); nm = fmaxf(m3, e); s3 = s3 * __expf(m3 - nm) + __expf(e - nm); m3 = nm;
    }
    #pragma unroll
    for (int off = 1; off < 64; off <<= 1){
        float om, os, nm;
        om = __shfl_xor(m0, off); os = __shfl_xor(s0, off);
        nm = fmaxf(m0, om); s0 = s0 * __expf(m0 - nm) + os * __expf(om - nm); m0 = nm;
        om = __shfl_xor(m1, off); os = __shfl_xor(s1, off);
        nm = fmaxf(m1, om); s1 = s1 * __expf(m1 - nm) + os * __expf(om - nm); m1 = nm;
        om = __shfl_xor(m2, off); os = __shfl_xor(s2, off);
        nm = fmaxf(m2, om); s2 = s2 * __expf(m2 - nm) + os * __expf(om - nm); m2 = nm;
        om = __shfl_xor(m3, off); os = __shfl_xor(s3, off);
        nm = fmaxf(m3, om); s3 = s3 * __expf(m3 - nm) + os * __expf(om - nm); m3 = nm;
    }
    float i0 = 1.f / s0, i1 = 1.f / s1, i2 = 1.f / s2, i3 = 1.f / s3;

    float acc0 = 0.f, acc1 = 0.f, acc2 = 0.f, acc3 = 0.f;
    for (int base = start; base < end; base += 64){
        int cnt = end - base; if (cnt > 64) cnt = 64;
        float w0 = 0.f, w1 = 0.f, w2 = 0.f, w3 = 0.f; int sm = 0;
        if (lane < cnt){
            int s = colsrc[base + lane];
            sm = s;
            float4 as = *(const float4*)(asrc + (size_t)s * 4);
            w0 = __expf(leaky(as.x + ad.x) - m0) * i0;
            w1 = __expf(leaky(as.y + ad.y) - m1) * i1;
            w2 = __expf(leaky(as.z + ad.z) - m2) * i2;
            w3 = __expf(leaky(as.w + ad.w) - m3) * i3;
        }
        for (int j = 0; j < cnt; ++j){
            int s = __shfl(sm, j);
            float a0 = __shfl(w0, j), a1 = __shfl(w1, j);
            float a2 = __shfl(w2, j), a3 = __shfl(w3, j);
            const __half* hs = h + (size_t)s * HC;
            acc0 = fmaf(a0, __half2float(hs[lane]),       acc0);
            acc1 = fmaf(a1, __half2float(hs[64 + lane]),  acc1);
            acc2 = fmaf(a2, __half2float(hs[128 + lane]), acc2);
            acc3 = fmaf(a3, __half2float(hs[192 + lane]), acc3);
        }
    }
    float o = (acc0 + acc1 + acc2 + acc3) * 0.25f + bias[lane];
    hout[(size_t)n * CH + lane] = (o > 0.f) ? o : expm1f(o);
}

// ---------------- scorer MLP ----------------

__global__ __launch_bounds__(256) void scorer_kernel(
    const float* __restrict__ h2, const float* __restrict__ donor,
    const float* __restrict__ Ws1, const float* __restrict__ bs1,
    const float* __restrict__ Ws2, const float* __restrict__ bs2,
    float* __restrict__ out, int N)
{
    __shared__ float Wl[96 * 64];
    __shared__ float d1[64];
    __shared__ float w2l[64];
    int tid = threadIdx.x;
    for (int i = tid; i < 96 * 64; i += 256) Wl[i] = Ws1[i];
    __syncthreads();
    if (tid < 64){
        float s = bs1[tid];
        for (int k = 0; k < 32; ++k) s = fmaf(donor[k], Wl[(64 + k) * 64 + tid], s);
        d1[tid] = s;
        w2l[tid] = Ws2[tid];
    }
    __syncthreads();
    int n = blockIdx.x * 256 + tid;
    if (n >= N) return;

    float hrow[64];
    const float4* hp = (const float4*)(h2 + (size_t)n * 64);
    #pragma unroll
    for (int i = 0; i < 16; ++i){
        float4 v = hp[i];
        hrow[4*i] = v.x; hrow[4*i+1] = v.y; hrow[4*i+2] = v.z; hrow[4*i+3] = v.w;
    }
    float logit = bs2[0];
    for (int j = 0; j < 64; ++j){
        float s = d1[j];
        #pragma unroll
        for (int k = 0; k < 64; ++k) s = fmaf(hrow[k], Wl[k * 64 + j], s);
        logit = fmaf(fmaxf(s, 0.f), w2l[j], logit);
    }
    out[n] = logit;
}

// ---------------- launch ----------------

extern "C" void kernel_launch(void* const* d_in, const int* in_sizes, int n_in,
                              void* d_out, int out_size, void* d_ws, size_t ws_size,
                              hipStream_t stream)
{
    const float* x    = (const float*)d_in[0];
    const int*   ei   = (const int*)  d_in[1];
    const float* donor= (const float*)d_in[2];
    const float* W1   = (const float*)d_in[3];
    const float* as1  = (const float*)d_in[4];
    const float* ad1  = (const float*)d_in[5];
    const float* b1   = (const float*)d_in[6];
    const float* W2   = (const float*)d_in[7];
    const float* as2  = (const float*)d_in[8];
    const float* ad2  = (const float*)d_in[9];
    const float* b2   = (const float*)d_in[10];
    const float* Ws1  = (const float*)d_in[11];
    const float* bs1  = (const float*)d_in[12];
    const float* Ws2  = (const float*)d_in[13];
    const float* bs2  = (const float*)d_in[14];

    const int N  = in_sizes[0] / 27;
    const int E  = in_sizes[1] / 2;
    const int ET = E + N;

    char* ws = (char*)d_ws;
    auto alloc = [&](size_t bytes) -> void* {
        void* p = (void*)ws;
        ws += (bytes + 255) / 256 * 256;
        return p;
    };
    int*    rowptr = (int*)   alloc((size_t)(N + 1) * 4);
    int*    deg    = (int*)   alloc((size_t)N * 4);
    int*    cursor = (int*)   alloc((size_t)N * 4);
    int*    colsrc = (int*)   alloc((size_t)ET * 4);
    __half* hbig   = (__half*)alloc((size_t)N * HC * 2);
    float*  asrc   = (float*) alloc((size_t)N * 4 * 4);
    float*  adst   = (float*) alloc((size_t)N * 4 * 4);
    float*  hmid   = (float*) alloc((size_t)N * CH * 4);
    const int SB = (N + SCAN_TILE - 1) / SCAN_TILE;
    int*    bsum   = (int*)   alloc((size_t)SB * 4);

    // CSR build
    hipMemsetAsync(deg, 0, (size_t)N * 4, stream);
    count_kernel<<<(ET + 255) / 256, 256, 0, stream>>>(ei, E, N, deg);
    blocksum_kernel<<<SB, 256, 0, stream>>>(deg, N, bsum);
    scan_bsum_kernel<<<1, 64, 0, stream>>>(bsum, SB, rowptr, N, ET);
    scan_write_kernel<<<SB, 256, 0, stream>>>(deg, bsum, N, rowptr, cursor);
    scatter_kernel<<<(ET + 255) / 256, 256, 0, stream>>>(ei, E, N, cursor, colsrc);

    const int nblk = (N + 63) / 64;

    // layer 1
    transform_mfma<27, 1, 16><<<dim3(nblk, 1), 256, 0, stream>>>(
        x, W1, as1, ad1, hbig, asrc, adst, N);
    aggregate_kernel<<<(N + 3) / 4, 256, 0, stream>>>(
        rowptr, colsrc, hbig, asrc, adst, b1, hmid, N);

    // layer 2
    transform_mfma<64, 2, 8><<<dim3(nblk, 2), 256, 0, stream>>>(
        hmid, W2, as2, ad2, hbig, asrc, adst, N);
    aggregate_kernel<<<(N + 3) / 4, 256, 0, stream>>>(
        rowptr, colsrc, hbig, asrc, adst, b2, hmid, N);

    // scorer
    scorer_kernel<<<(N + 255) / 256, 256, 0, stream>>>(
        hmid, donor, Ws1, bs1, Ws2, bs2, (float*)d_out, N);
}

// Round 5
// 411.244 us; speedup vs baseline: 1.7887x; 1.1175x over previous
//
#include <hip/hip_runtime.h>
#include <hip/hip_fp16.h>
#include <cmath>

#define HEADS 4
#define CH 64
#define HC 256
#define NEG 0.2f
#define SCAN_TILE 2048

typedef __attribute__((ext_vector_type(8))) short short8;
typedef __attribute__((ext_vector_type(4))) float f32x4;
typedef __fp16 half2_t __attribute__((ext_vector_type(2)));

__device__ __forceinline__ float leaky(float v){ return v > 0.f ? v : NEG * v; }

__device__ __forceinline__ short bf16_rne(float f){
    unsigned u = __float_as_uint(f);
    unsigned r = u + 0x7fffu + ((u >> 16) & 1u);
    return (short)(r >> 16);
}
__device__ __forceinline__ float bf16_to_f(short s){
    return __uint_as_float(((unsigned)(unsigned short)s) << 16);
}
__device__ __forceinline__ half2_t bc16(unsigned u){ return __builtin_bit_cast(half2_t, u); }

// ---------------- CSR build (counting sort by dst) ----------------

__global__ void count_kernel(const int* __restrict__ ei, int E, int N, int* __restrict__ deg){
    int e = blockIdx.x * 256 + threadIdx.x;
    int ET = E + N;
    if (e >= ET) return;
    int d = (e < E) ? ei[E + e] : (e - E);
    atomicAdd(&deg[d], 1);
}

__global__ void blocksum_kernel(const int* __restrict__ deg, int N, int* __restrict__ bsum){
    __shared__ int wsum[4];
    int tid = threadIdx.x;
    int base = blockIdx.x * SCAN_TILE;
    int s = 0;
    for (int i = tid; i < SCAN_TILE; i += 256){
        int idx = base + i;
        s += (idx < N) ? deg[idx] : 0;
    }
    #pragma unroll
    for (int off = 32; off > 0; off >>= 1) s += __shfl_down(s, off);
    if ((tid & 63) == 0) wsum[tid >> 6] = s;
    __syncthreads();
    if (tid == 0) bsum[blockIdx.x] = wsum[0] + wsum[1] + wsum[2] + wsum[3];
}

__global__ void scan_bsum_kernel(int* __restrict__ bsum, int B, int* __restrict__ rowptr, int N, int ET){
    if (threadIdx.x == 0){
        int acc = 0;
        for (int i = 0; i < B; ++i){ int c = bsum[i]; bsum[i] = acc; acc += c; }
        rowptr[N] = ET;
    }
}

__global__ void scan_write_kernel(const int* __restrict__ deg, const int* __restrict__ bsum,
                                  int N, int* __restrict__ rowptr, int* __restrict__ cursor){
    __shared__ int wsum[4];
    int tid = threadIdx.x;
    int base = blockIdx.x * SCAN_TILE + tid * 8;
    int v[8]; int s = 0;
    #pragma unroll
    for (int j = 0; j < 8; ++j){
        int idx = base + j;
        v[j] = (idx < N) ? deg[idx] : 0;
        s += v[j];
    }
    int lane = tid & 63, wv = tid >> 6;
    int incl = s;
    #pragma unroll
    for (int off = 1; off < 64; off <<= 1){
        int t = __shfl_up(incl, off);
        if (lane >= off) incl += t;
    }
    if (lane == 63) wsum[wv] = incl;
    __syncthreads();
    int excl = incl - s + bsum[blockIdx.x];
    for (int w = 0; w < wv; ++w) excl += wsum[w];
    #pragma unroll
    for (int j = 0; j < 8; ++j){
        int idx = base + j;
        if (idx < N){ rowptr[idx] = excl; cursor[idx] = excl; excl += v[j]; }
    }
}

__global__ void scatter_kernel(const int* __restrict__ ei, int E, int N,
                               int* __restrict__ cursor, int* __restrict__ colsrc){
    int e = blockIdx.x * 256 + threadIdx.x;
    int ET = E + N;
    if (e >= ET) return;
    int s, d;
    if (e < E){ s = ei[e]; d = ei[E + e]; } else { s = d = e - E; }
    int pos = atomicAdd(&cursor[d], 1);
    colsrc[pos] = s;
}

// ---------------- MFMA node transform ----------------
// h output layout INTERLEAVED: h[n][ch][head] (4 halves per channel, 8B per lane).

template<int FIN, int KSTEPS, int NT>
__global__ __launch_bounds__(256) void transform_mfma(
    const float* __restrict__ xin, const float* __restrict__ W,
    const float* __restrict__ a_src, const float* __restrict__ a_dst,
    __half* __restrict__ h, float* __restrict__ asrc, float* __restrict__ adst,
    int N)
{
    constexpr int KP = KSTEPS * 32;
    constexpr int XP = KP + 4;
    constexpr int WP = KP + 8;
    constexpr int NCOL = NT * 16;
    __shared__ float xl[64 * XP];
    __shared__ short wt_hi[NCOL * WP];
    __shared__ short wt_lo[NCOL * WP];

    const int tid = threadIdx.x;
    const int n0 = blockIdx.x * 64;
    const int c0 = blockIdx.y * NCOL;

    if (FIN == 64) {
        for (int t = tid; t < 64 * 16; t += 256) {
            int row = t >> 4, c4 = (t & 15) * 4;
            int n = n0 + row;
            float4 v = make_float4(0.f, 0.f, 0.f, 0.f);
            if (n < N) v = *(const float4*)(xin + (size_t)n * 64 + c4);
            *(float4*)(xl + row * XP + c4) = v;
        }
    } else {
        for (int t = tid; t < 64 * KP; t += 256) {
            int row = t / KP, k = t % KP;
            int n = n0 + row;
            float v = 0.f;
            if (n < N && k < FIN) v = xin[(size_t)n * FIN + k];
            xl[row * XP + k] = v;
        }
    }
    // coalesced W stage: consecutive lanes read consecutive columns
    for (int t = tid; t < NCOL * KP; t += 256) {
        int k = t / NCOL, n = t % NCOL;
        float v = (k < FIN) ? W[(size_t)k * HC + c0 + n] : 0.f;
        short hi = bf16_rne(v);
        wt_hi[n * WP + k] = hi;
        wt_lo[n * WP + k] = bf16_rne(v - bf16_to_f(hi));
    }
    __syncthreads();

    const int wv = tid >> 6, lane = tid & 63;
    const int quad = lane >> 4, ln = lane & 15;
    const int myrow = wv * 16 + ln;

    f32x4 acc[NT];
    #pragma unroll
    for (int i = 0; i < NT; ++i) acc[i] = (f32x4){0.f, 0.f, 0.f, 0.f};

    #pragma unroll
    for (int ks = 0; ks < KSTEPS; ++ks) {
        const int k0 = ks * 32 + quad * 8;
        const float* ap = xl + myrow * XP + k0;
        float4 f0 = *(const float4*)ap;
        float4 f1 = *(const float4*)(ap + 4);
        float fa[8] = {f0.x, f0.y, f0.z, f0.w, f1.x, f1.y, f1.z, f1.w};
        short8 ahi, alo;
        #pragma unroll
        for (int e = 0; e < 8; ++e) {
            short hi = bf16_rne(fa[e]);
            ahi[e] = hi;
            alo[e] = bf16_rne(fa[e] - bf16_to_f(hi));
        }
        #pragma unroll
        for (int nt = 0; nt < NT; ++nt) {
            short8 bhi = *(const short8*)(wt_hi + (nt * 16 + ln) * WP + k0);
            short8 blo = *(const short8*)(wt_lo + (nt * 16 + ln) * WP + k0);
            acc[nt] = __builtin_amdgcn_mfma_f32_16x16x32_bf16(ahi, bhi, acc[nt], 0, 0, 0);
            acc[nt] = __builtin_amdgcn_mfma_f32_16x16x32_bf16(alo, bhi, acc[nt], 0, 0, 0);
            acc[nt] = __builtin_amdgcn_mfma_f32_16x16x32_bf16(ahi, blo, acc[nt], 0, 0, 0);
        }
    }

    // write h interleaved [n][ch][head]
    #pragma unroll
    for (int r = 0; r < 4; ++r) {
        int n = n0 + wv * 16 + quad * 4 + r;
        if (n < N) {
            #pragma unroll
            for (int nt = 0; nt < NT; ++nt) {
                int col = c0 + nt * 16 + ln;
                h[(size_t)n * HC + (col & 63) * 4 + (col >> 6)] = __float2half(acc[nt][r]);
            }
        }
    }

    float aS[NT], aD[NT];
    #pragma unroll
    for (int nt = 0; nt < NT; ++nt) {
        aS[nt] = a_src[c0 + nt * 16 + ln];
        aD[nt] = a_dst[c0 + nt * 16 + ln];
    }
    #pragma unroll
    for (int hl = 0; hl < NT / 4; ++hl) {
        #pragma unroll
        for (int r = 0; r < 4; ++r) {
            float ps = 0.f, pd = 0.f;
            #pragma unroll
            for (int i = 0; i < 4; ++i) {
                ps = fmaf(acc[hl * 4 + i][r], aS[hl * 4 + i], ps);
                pd = fmaf(acc[hl * 4 + i][r], aD[hl * 4 + i], pd);
            }
            #pragma unroll
            for (int off = 1; off < 16; off <<= 1) {
                ps += __shfl_xor(ps, off);
                pd += __shfl_xor(pd, off);
            }
            if (ln == 0) {
                int n = n0 + wv * 16 + quad * 4 + r;
                if (n < N) {
                    int hg = c0 / 64 + hl;
                    asrc[n * 4 + hg] = ps;
                    adst[n * 4 + hg] = pd;
                }
            }
        }
    }
}

// ---------------- per-dst aggregation (one wave per node) ----------------
// pass A: lane-parallel online softmax (e cached in regs for first chunk).
// pass B: per-edge dot2 accumulate; weights/offsets broadcast via LDS,
//         scalar-base loads, heads mixed in one fp32 acc (legal under head-mean).

__device__ __forceinline__ void edge_sweep(
    const int* __restrict__ soff, const uint2* __restrict__ sw,
    const __half* __restrict__ h, int boff, int cnt, float& accA, float& accB)
{
    int cnt2 = (cnt + 1) & ~1;
    for (int j = 0; j < cnt2; j += 2){
        int offA = __builtin_amdgcn_readfirstlane(soff[j]);
        int offB = __builtin_amdgcn_readfirstlane(soff[j + 1]);
        uint4 w4 = *(const uint4*)(sw + j);
        uint2 ha = *(const uint2*)((const char*)h + offA + boff);
        uint2 hb = *(const uint2*)((const char*)h + offB + boff);
        accA = __builtin_amdgcn_fdot2(bc16(ha.x), bc16(w4.x), accA, false);
        accA = __builtin_amdgcn_fdot2(bc16(ha.y), bc16(w4.y), accA, false);
        accB = __builtin_amdgcn_fdot2(bc16(hb.x), bc16(w4.z), accB, false);
        accB = __builtin_amdgcn_fdot2(bc16(hb.y), bc16(w4.w), accB, false);
    }
}

__global__ __launch_bounds__(256) void aggregate_kernel(
    const int* __restrict__ rowptr, const int* __restrict__ colsrc,
    const __half* __restrict__ h, const float* __restrict__ asrc,
    const float* __restrict__ adst, const float* __restrict__ bias,
    float* __restrict__ hout, int N)
{
    __shared__ int  s_off[4][64];
    __shared__ uint2 s_w[4][64];
    int wv = threadIdx.x >> 6, lane = threadIdx.x & 63;
    int n = blockIdx.x * 4 + wv;
    if (n >= N) return;
    int start = rowptr[n], end = rowptr[n + 1];
    int deg = end - start;
    const float4 ad = *(const float4*)(adst + (size_t)n * 4);

    // ---- pass A: online softmax stats; cache first-chunk e + src in regs
    int src0 = 0;
    float e0 = -1e30f, e1 = -1e30f, e2 = -1e30f, e3 = -1e30f;
    bool v0 = lane < deg;
    if (v0){
        src0 = colsrc[start + lane];
        float4 as = *(const float4*)(asrc + (size_t)src0 * 4);
        e0 = leaky(as.x + ad.x); e1 = leaky(as.y + ad.y);
        e2 = leaky(as.z + ad.z); e3 = leaky(as.w + ad.w);
    }
    float m0 = e0, m1 = e1, m2 = e2, m3 = e3;
    float t0 = v0 ? 1.f : 0.f, t1 = t0, t2 = t0, t3 = t0;
    for (int i = start + 64 + lane; i < end; i += 64){
        int s = colsrc[i];
        float4 as = *(const float4*)(asrc + (size_t)s * 4);
        float e, nm;
        e = leaky(as.x + ad.x); nm = fmaxf(m0, e); t0 = t0 * __expf(m0 - nm) + __expf(e - nm); m0 = nm;
        e = leaky(as.y + ad.y); nm = fmaxf(m1, e); t1 = t1 * __expf(m1 - nm) + __expf(e - nm); m1 = nm;
        e = leaky(as.z + ad.z); nm = fmaxf(m2, e); t2 = t2 * __expf(m2 - nm) + __expf(e - nm); m2 = nm;
        e = leaky(as.w + ad.w); nm = fmaxf(m3, e); t3 = t3 * __expf(m3 - nm) + __expf(e - nm); m3 = nm;
    }
    #pragma unroll
    for (int off = 1; off < 64; off <<= 1){
        float om, os, nm;
        om = __shfl_xor(m0, off); os = __shfl_xor(t0, off);
        nm = fmaxf(m0, om); t0 = t0 * __expf(m0 - nm) + os * __expf(om - nm); m0 = nm;
        om = __shfl_xor(m1, off); os = __shfl_xor(t1, off);
        nm = fmaxf(m1, om); t1 = t1 * __expf(m1 - nm) + os * __expf(om - nm); m1 = nm;
        om = __shfl_xor(m2, off); os = __shfl_xor(t2, off);
        nm = fmaxf(m2, om); t2 = t2 * __expf(m2 - nm) + os * __expf(om - nm); m2 = nm;
        om = __shfl_xor(m3, off); os = __shfl_xor(t3, off);
        nm = fmaxf(m3, om); t3 = t3 * __expf(m3 - nm) + os * __expf(om - nm); m3 = nm;
    }
    float i0 = 1.f / t0, i1 = 1.f / t1, i2 = 1.f / t2, i3 = 1.f / t3;

    // ---- pass B
    float accA = 0.f, accB = 0.f;
    const int boff = lane * 8;   // byte offset: lane's channel (uint2 of 4 halves)

    // chunk 0 from cached regs (exp underflows to 0 for invalid lanes)
    {
        float w0 = __expf(e0 - m0) * i0;
        float w1 = __expf(e1 - m1) * i1;
        float w2 = __expf(e2 - m2) * i2;
        float w3 = __expf(e3 - m3) * i3;
        int off = v0 ? src0 * (HC * 2) : 0;
        s_off[wv][lane] = off;
        half2_t p01 = __builtin_amdgcn_cvt_pkrtz(w0, w1);
        half2_t p23 = __builtin_amdgcn_cvt_pkrtz(w2, w3);
        s_w[wv][lane] = (uint2){ __builtin_bit_cast(unsigned, p01),
                                 __builtin_bit_cast(unsigned, p23) };
        int cnt = deg < 64 ? deg : 64;
        edge_sweep(&s_off[wv][0], &s_w[wv][0], h, boff, cnt, accA, accB);
    }
    // rare extra chunks (deg > 64)
    for (int base = start + 64; base < end; base += 64){
        int cnt = end - base; if (cnt > 64) cnt = 64;
        float w0 = 0.f, w1 = 0.f, w2 = 0.f, w3 = 0.f; int off = 0;
        if (lane < cnt){
            int s = colsrc[base + lane];
            float4 as = *(const float4*)(asrc + (size_t)s * 4);
            w0 = __expf(leaky(as.x + ad.x) - m0) * i0;
            w1 = __expf(leaky(as.y + ad.y) - m1) * i1;
            w2 = __expf(leaky(as.z + ad.z) - m2) * i2;
            w3 = __expf(leaky(as.w + ad.w) - m3) * i3;
            off = s * (HC * 2);
        }
        s_off[wv][lane] = off;
        half2_t p01 = __builtin_amdgcn_cvt_pkrtz(w0, w1);
        half2_t p23 = __builtin_amdgcn_cvt_pkrtz(w2, w3);
        s_w[wv][lane] = (uint2){ __builtin_bit_cast(unsigned, p01),
                                 __builtin_bit_cast(unsigned, p23) };
        edge_sweep(&s_off[wv][0], &s_w[wv][0], h, boff, cnt, accA, accB);
    }

    float o = (accA + accB) * 0.25f + bias[lane];
    hout[(size_t)n * CH + lane] = (o > 0.f) ? o : expm1f(o);
}

// ---------------- scorer MLP ----------------

__global__ __launch_bounds__(256) void scorer_kernel(
    const float* __restrict__ h2, const float* __restrict__ donor,
    const float* __restrict__ Ws1, const float* __restrict__ bs1,
    const float* __restrict__ Ws2, const float* __restrict__ bs2,
    float* __restrict__ out, int N)
{
    __shared__ float Wl[96 * 64];
    __shared__ float d1[64];
    __shared__ float w2l[64];
    int tid = threadIdx.x;
    for (int i = tid; i < 96 * 64; i += 256) Wl[i] = Ws1[i];
    __syncthreads();
    if (tid < 64){
        float s = bs1[tid];
        for (int k = 0; k < 32; ++k) s = fmaf(donor[k], Wl[(64 + k) * 64 + tid], s);
        d1[tid] = s;
        w2l[tid] = Ws2[tid];
    }
    __syncthreads();
    int n = blockIdx.x * 256 + tid;
    if (n >= N) return;

    float hrow[64];
    const float4* hp = (const float4*)(h2 + (size_t)n * 64);
    #pragma unroll
    for (int i = 0; i < 16; ++i){
        float4 v = hp[i];
        hrow[4*i] = v.x; hrow[4*i+1] = v.y; hrow[4*i+2] = v.z; hrow[4*i+3] = v.w;
    }
    float logit = bs2[0];
    for (int j = 0; j < 64; ++j){
        float s = d1[j];
        #pragma unroll
        for (int k = 0; k < 64; ++k) s = fmaf(hrow[k], Wl[k * 64 + j], s);
        logit = fmaf(fmaxf(s, 0.f), w2l[j], logit);
    }
    out[n] = logit;
}

// ---------------- launch ----------------

extern "C" void kernel_launch(void* const* d_in, const int* in_sizes, int n_in,
                              void* d_out, int out_size, void* d_ws, size_t ws_size,
                              hipStream_t stream)
{
    const float* x    = (const float*)d_in[0];
    const int*   ei   = (const int*)  d_in[1];
    const float* donor= (const float*)d_in[2];
    const float* W1   = (const float*)d_in[3];
    const float* as1  = (const float*)d_in[4];
    const float* ad1  = (const float*)d_in[5];
    const float* b1   = (const float*)d_in[6];
    const float* W2   = (const float*)d_in[7];
    const float* as2  = (const float*)d_in[8];
    const float* ad2  = (const float*)d_in[9];
    const float* b2   = (const float*)d_in[10];
    const float* Ws1  = (const float*)d_in[11];
    const float* bs1  = (const float*)d_in[12];
    const float* Ws2  = (const float*)d_in[13];
    const float* bs2  = (const float*)d_in[14];

    const int N  = in_sizes[0] / 27;
    const int E  = in_sizes[1] / 2;
    const int ET = E + N;

    char* ws = (char*)d_ws;
    auto alloc = [&](size_t bytes) -> void* {
        void* p = (void*)ws;
        ws += (bytes + 255) / 256 * 256;
        return p;
    };
    int*    rowptr = (int*)   alloc((size_t)(N + 1) * 4);
    int*    deg    = (int*)   alloc((size_t)N * 4);
    int*    cursor = (int*)   alloc((size_t)N * 4);
    int*    colsrc = (int*)   alloc((size_t)ET * 4);
    __half* hbig   = (__half*)alloc((size_t)N * HC * 2);
    float*  asrc   = (float*) alloc((size_t)N * 4 * 4);
    float*  adst   = (float*) alloc((size_t)N * 4 * 4);
    float*  hmid   = (float*) alloc((size_t)N * CH * 4);
    const int SB = (N + SCAN_TILE - 1) / SCAN_TILE;
    int*    bsum   = (int*)   alloc((size_t)SB * 4);

    (void)hipMemsetAsync(deg, 0, (size_t)N * 4, stream);
    count_kernel<<<(ET + 255) / 256, 256, 0, stream>>>(ei, E, N, deg);
    blocksum_kernel<<<SB, 256, 0, stream>>>(deg, N, bsum);
    scan_bsum_kernel<<<1, 64, 0, stream>>>(bsum, SB, rowptr, N, ET);
    scan_write_kernel<<<SB, 256, 0, stream>>>(deg, bsum, N, rowptr, cursor);
    scatter_kernel<<<(ET + 255) / 256, 256, 0, stream>>>(ei, E, N, cursor, colsrc);

    const int nblk = (N + 63) / 64;

    transform_mfma<27, 1, 16><<<dim3(nblk, 1), 256, 0, stream>>>(
        x, W1, as1, ad1, hbig, asrc, adst, N);
    aggregate_kernel<<<(N + 3) / 4, 256, 0, stream>>>(
        rowptr, colsrc, hbig, asrc, adst, b1, hmid, N);

    transform_mfma<64, 2, 8><<<dim3(nblk, 2), 256, 0, stream>>>(
        hmid, W2, as2, ad2, hbig, asrc, adst, N);
    aggregate_kernel<<<(N + 3) / 4, 256, 0, stream>>>(
        rowptr, colsrc, hbig, asrc, adst, b2, hmid, N);

    scorer_kernel<<<(N + 255) / 256, 256, 0, stream>>>(
        hmid, donor, Ws1, bs1, Ws2, bs2, (float*)d_out, N);
}

// Round 6
// 362.594 us; speedup vs baseline: 2.0286x; 1.1342x over previous
//
#include <hip/hip_runtime.h>
#include <hip/hip_fp16.h>
#include <cmath>

#define HEADS 4
#define CH 64
#define HC 256
#define NEG 0.2f
#define SCAN_TILE 2048

typedef __attribute__((ext_vector_type(8))) short short8;
typedef __attribute__((ext_vector_type(4))) float f32x4;
typedef __fp16 half2_t __attribute__((ext_vector_type(2)));

__device__ __forceinline__ float leaky(float v){ return v > 0.f ? v : NEG * v; }

__device__ __forceinline__ short bf16_rne(float f){
    unsigned u = __float_as_uint(f);
    unsigned r = u + 0x7fffu + ((u >> 16) & 1u);
    return (short)(r >> 16);
}
__device__ __forceinline__ float bf16_to_f(short s){
    return __uint_as_float(((unsigned)(unsigned short)s) << 16);
}
__device__ __forceinline__ half2_t bc16(unsigned u){ return __builtin_bit_cast(half2_t, u); }
__device__ __forceinline__ unsigned packh2(float a, float b){
    __half ha = __float2half(a), hb = __float2half(b);   // RNE
    return (unsigned)__builtin_bit_cast(unsigned short, ha)
         | ((unsigned)__builtin_bit_cast(unsigned short, hb) << 16);
}

// ---------------- prep: zero deg + one-time bf16-split of weights + d1 ----------------

__global__ __launch_bounds__(256) void prep_kernel(
    const float* __restrict__ W1, const float* __restrict__ W2,
    const float* __restrict__ Ws1, const float* __restrict__ bs1,
    const float* __restrict__ donor,
    int* __restrict__ deg, short* __restrict__ w1hi, short* __restrict__ w1lo,
    short* __restrict__ w2hi, short* __restrict__ w2lo,
    short* __restrict__ s1hi, short* __restrict__ s1lo,
    float* __restrict__ d1p, int N)
{
    int t = blockIdx.x * 256 + threadIdx.x;
    int T = gridDim.x * 256;
    for (int i = t; i < N; i += T) deg[i] = 0;
    for (int i = t; i < 256 * 40; i += T){                  // W1: [n=256][k pitch 40], K=27
        int n = i / 40, k = i % 40;
        float v = (k < 27) ? W1[(size_t)k * HC + n] : 0.f;
        short hi = bf16_rne(v);
        w1hi[i] = hi; w1lo[i] = bf16_rne(v - bf16_to_f(hi));
    }
    for (int i = t; i < 256 * 72; i += T){                  // W2: [n=256][k pitch 72], K=64
        int n = i / 72, k = i % 72;
        float v = (k < 64) ? W2[(size_t)k * HC + n] : 0.f;
        short hi = bf16_rne(v);
        w2hi[i] = hi; w2lo[i] = bf16_rne(v - bf16_to_f(hi));
    }
    for (int i = t; i < 64 * 72; i += T){                   // Ws1 h-part: [j=64][k pitch 72], K=64
        int n = i / 72, k = i % 72;
        float v = (k < 64) ? Ws1[(size_t)k * 64 + n] : 0.f;
        short hi = bf16_rne(v);
        s1hi[i] = hi; s1lo[i] = bf16_rne(v - bf16_to_f(hi));
    }
    if (t < 64){                                            // d1 = bs1 + donor @ Ws1[64:96]
        float s = bs1[t];
        for (int k = 0; k < 32; ++k) s = fmaf(donor[k], Ws1[(size_t)(64 + k) * 64 + t], s);
        d1p[t] = s;
    }
}

// ---------------- CSR build ----------------

__global__ void blocksum_kernel(const int* __restrict__ deg, int N, int* __restrict__ bsum){
    __shared__ int wsum[4];
    int tid = threadIdx.x;
    int base = blockIdx.x * SCAN_TILE;
    int s = 0;
    for (int i = tid; i < SCAN_TILE; i += 256){
        int idx = base + i;
        s += (idx < N) ? deg[idx] : 0;
    }
    #pragma unroll
    for (int off = 32; off > 0; off >>= 1) s += __shfl_down(s, off);
    if ((tid & 63) == 0) wsum[tid >> 6] = s;
    __syncthreads();
    if (tid == 0) bsum[blockIdx.x] = wsum[0] + wsum[1] + wsum[2] + wsum[3];
}

// each block self-scans the (<=64) bsum partials; also writes rowptr[N]
__global__ void scan_write_kernel(const int* __restrict__ deg, const int* __restrict__ bsum,
                                  int N, int ET, int* __restrict__ rowptr, int* __restrict__ cursor){
    __shared__ int wsum[4];
    __shared__ int bpre;
    int tid = threadIdx.x;
    if (tid < 64){
        int v = (tid < blockIdx.x) ? bsum[tid] : 0;
        #pragma unroll
        for (int off = 32; off > 0; off >>= 1) v += __shfl_down(v, off);
        if (tid == 0) bpre = v;
    }
    if (blockIdx.x == 0 && tid == 0) rowptr[N] = ET;
    int base = blockIdx.x * SCAN_TILE + tid * 8;
    int v[8]; int s = 0;
    #pragma unroll
    for (int j = 0; j < 8; ++j){
        int idx = base + j;
        v[j] = (idx < N) ? deg[idx] : 0;
        s += v[j];
    }
    int lane = tid & 63, wv = tid >> 6;
    int incl = s;
    #pragma unroll
    for (int off = 1; off < 64; off <<= 1){
        int tt = __shfl_up(incl, off);
        if (lane >= off) incl += tt;
    }
    if (lane == 63) wsum[wv] = incl;
    __syncthreads();
    int excl = incl - s + bpre;
    for (int w = 0; w < wv; ++w) excl += wsum[w];
    #pragma unroll
    for (int j = 0; j < 8; ++j){
        int idx = base + j;
        if (idx < N){ rowptr[idx] = excl; cursor[idx] = excl; excl += v[j]; }
    }
}

__global__ void scatter_kernel(const int* __restrict__ ei, int E, int N,
                               int* __restrict__ cursor, int* __restrict__ colsrc){
    int e = blockIdx.x * 256 + threadIdx.x;
    int ET = E + N;
    if (e >= ET) return;
    int s, d;
    if (e < E){ s = ei[e]; d = ei[E + e]; } else { s = d = e - E; }
    int pos = atomicAdd(&cursor[d], 1);
    colsrc[pos] = s;
}

// ---------------- MFMA node transform (device body) ----------------
// Pre-split W from global (pitch WP). h written packed: [n][ch][head] 4 halves/slot.

template<int FIN, int KSTEPS, int NT>
__device__ __forceinline__ void transform_body(
    int bx, int by,
    const float* __restrict__ xin, const short* __restrict__ whi, const short* __restrict__ wlo,
    const float* __restrict__ a_src, const float* __restrict__ a_dst,
    __half* __restrict__ h, float* __restrict__ asrc, float* __restrict__ adst, int N)
{
    constexpr int KP = KSTEPS * 32;
    constexpr int XP = KP + 4;
    constexpr int WP = KP + 8;
    constexpr int NCOL = NT * 16;
    __shared__ float xl[64 * XP];
    __shared__ short wt_hi[NCOL * WP];
    __shared__ short wt_lo[NCOL * WP];

    const int tid = threadIdx.x;
    const int n0 = bx * 64;
    const int c0 = by * NCOL;

    if (FIN == 64) {
        for (int t = tid; t < 64 * 16; t += 256) {
            int row = t >> 4, c4 = (t & 15) * 4;
            int n = n0 + row;
            float4 v = make_float4(0.f, 0.f, 0.f, 0.f);
            if (n < N) v = *(const float4*)(xin + (size_t)n * 64 + c4);
            *(float4*)(xl + row * XP + c4) = v;
        }
    } else {
        for (int t = tid; t < 64 * KP; t += 256) {
            int row = t / KP, k = t % KP;
            int n = n0 + row;
            float v = 0.f;
            if (n < N && k < FIN) v = xin[(size_t)n * FIN + k];
            xl[row * XP + k] = v;
        }
    }
    // straight copy of pre-split W slice (layout identical to LDS)
    {
        const short8* ghi = (const short8*)(whi + (size_t)c0 * WP);
        const short8* glo = (const short8*)(wlo + (size_t)c0 * WP);
        short8* lhi = (short8*)wt_hi;
        short8* llo = (short8*)wt_lo;
        for (int t = tid; t < NCOL * WP / 8; t += 256){
            lhi[t] = ghi[t];
            llo[t] = glo[t];
        }
    }
    __syncthreads();

    const int wv = tid >> 6, lane = tid & 63;
    const int quad = lane >> 4, ln = lane & 15;
    const int myrow = wv * 16 + ln;

    f32x4 acc[NT];
    #pragma unroll
    for (int i = 0; i < NT; ++i) acc[i] = (f32x4){0.f, 0.f, 0.f, 0.f};

    #pragma unroll
    for (int ks = 0; ks < KSTEPS; ++ks) {
        const int k0 = ks * 32 + quad * 8;
        const float* ap = xl + myrow * XP + k0;
        float4 f0 = *(const float4*)ap;
        float4 f1 = *(const float4*)(ap + 4);
        float fa[8] = {f0.x, f0.y, f0.z, f0.w, f1.x, f1.y, f1.z, f1.w};
        short8 ahi, alo;
        #pragma unroll
        for (int e = 0; e < 8; ++e) {
            short hi = bf16_rne(fa[e]);
            ahi[e] = hi;
            alo[e] = bf16_rne(fa[e] - bf16_to_f(hi));
        }
        #pragma unroll
        for (int nt = 0; nt < NT; ++nt) {
            short8 bhi = *(const short8*)(wt_hi + (nt * 16 + ln) * WP + k0);
            short8 blo = *(const short8*)(wt_lo + (nt * 16 + ln) * WP + k0);
            acc[nt] = __builtin_amdgcn_mfma_f32_16x16x32_bf16(ahi, bhi, acc[nt], 0, 0, 0);
            acc[nt] = __builtin_amdgcn_mfma_f32_16x16x32_bf16(alo, bhi, acc[nt], 0, 0, 0);
            acc[nt] = __builtin_amdgcn_mfma_f32_16x16x32_bf16(ahi, blo, acc[nt], 0, 0, 0);
        }
    }

    // packed h write: slot (n, ch=q*16+ln) holds 4 halves [head0..3]
    #pragma unroll
    for (int r = 0; r < 4; ++r) {
        int n = n0 + wv * 16 + quad * 4 + r;
        if (n < N) {
            if (NT == 16) {        // layer1: all 4 heads present
                #pragma unroll
                for (int q = 0; q < 4; ++q) {
                    uint2 u;
                    u.x = packh2(acc[q][r],     acc[q + 4][r]);
                    u.y = packh2(acc[q + 8][r], acc[q + 12][r]);
                    *(uint2*)((char*)h + (size_t)n * 512 + (q * 16 + ln) * 8) = u;
                }
            } else {               // layer2 split: 2 heads per block (c0 selects half)
                #pragma unroll
                for (int q = 0; q < 4; ++q) {
                    unsigned u = packh2(acc[q][r], acc[q + 4][r]);
                    *(unsigned*)((char*)h + (size_t)n * 512 + (q * 16 + ln) * 8 + ((c0 >> 6) << 1)) = u;
                }
            }
        }
    }

    float aS[NT], aD[NT];
    #pragma unroll
    for (int nt = 0; nt < NT; ++nt) {
        aS[nt] = a_src[c0 + nt * 16 + ln];
        aD[nt] = a_dst[c0 + nt * 16 + ln];
    }
    #pragma unroll
    for (int hl = 0; hl < NT / 4; ++hl) {
        #pragma unroll
        for (int r = 0; r < 4; ++r) {
            float ps = 0.f, pd = 0.f;
            #pragma unroll
            for (int i = 0; i < 4; ++i) {
                ps = fmaf(acc[hl * 4 + i][r], aS[hl * 4 + i], ps);
                pd = fmaf(acc[hl * 4 + i][r], aD[hl * 4 + i], pd);
            }
            #pragma unroll
            for (int off = 1; off < 16; off <<= 1) {
                ps += __shfl_xor(ps, off);
                pd += __shfl_xor(pd, off);
            }
            if (ln == 0) {
                int n = n0 + wv * 16 + quad * 4 + r;
                if (n < N) {
                    int hg = c0 / 64 + hl;
                    asrc[n * 4 + hg] = ps;
                    adst[n * 4 + hg] = pd;
                }
            }
        }
    }
}

// layer1 transform fused with edge counting (independent work, shared grid)
__global__ __launch_bounds__(256) void transform1_count_kernel(
    const float* __restrict__ xin, const short* __restrict__ whi, const short* __restrict__ wlo,
    const float* __restrict__ a_src, const float* __restrict__ a_dst,
    __half* __restrict__ h, float* __restrict__ asrc, float* __restrict__ adst, int N,
    int nblk, const int* __restrict__ ei, int E, int* __restrict__ deg)
{
    if ((int)blockIdx.x < nblk) {
        transform_body<27, 1, 16>(blockIdx.x, 0, xin, whi, wlo, a_src, a_dst, h, asrc, adst, N);
    } else {
        int e = (blockIdx.x - nblk) * 256 + threadIdx.x;
        int ET = E + N;
        if (e < ET){
            int d = (e < E) ? ei[E + e] : (e - E);
            atomicAdd(&deg[d], 1);
        }
    }
}

__global__ __launch_bounds__(256) void transform2_kernel(
    const float* __restrict__ xin, const short* __restrict__ whi, const short* __restrict__ wlo,
    const float* __restrict__ a_src, const float* __restrict__ a_dst,
    __half* __restrict__ h, float* __restrict__ asrc, float* __restrict__ adst, int N)
{
    transform_body<64, 2, 8>(blockIdx.x, blockIdx.y, xin, whi, wlo, a_src, a_dst, h, asrc, adst, N);
}

// ---------------- per-dst aggregation (unchanged from R5) ----------------

__device__ __forceinline__ void edge_sweep(
    const int* __restrict__ soff, const uint2* __restrict__ sw,
    const __half* __restrict__ h, int boff, int cnt, float& accA, float& accB)
{
    int cnt2 = (cnt + 1) & ~1;
    for (int j = 0; j < cnt2; j += 2){
        int offA = __builtin_amdgcn_readfirstlane(soff[j]);
        int offB = __builtin_amdgcn_readfirstlane(soff[j + 1]);
        uint4 w4 = *(const uint4*)(sw + j);
        uint2 ha = *(const uint2*)((const char*)h + offA + boff);
        uint2 hb = *(const uint2*)((const char*)h + offB + boff);
        accA = __builtin_amdgcn_fdot2(bc16(ha.x), bc16(w4.x), accA, false);
        accA = __builtin_amdgcn_fdot2(bc16(ha.y), bc16(w4.y), accA, false);
        accB = __builtin_amdgcn_fdot2(bc16(hb.x), bc16(w4.z), accB, false);
        accB = __builtin_amdgcn_fdot2(bc16(hb.y), bc16(w4.w), accB, false);
    }
}

__global__ __launch_bounds__(256) void aggregate_kernel(
    const int* __restrict__ rowptr, const int* __restrict__ colsrc,
    const __half* __restrict__ h, const float* __restrict__ asrc,
    const float* __restrict__ adst, const float* __restrict__ bias,
    float* __restrict__ hout, int N)
{
    __shared__ int  s_off[4][64];
    __shared__ uint2 s_w[4][64];
    int wv = threadIdx.x >> 6, lane = threadIdx.x & 63;
    int n = blockIdx.x * 4 + wv;
    if (n >= N) return;
    int start = rowptr[n], end = rowptr[n + 1];
    int deg = end - start;
    const float4 ad = *(const float4*)(adst + (size_t)n * 4);

    int src0 = 0;
    float e0 = -1e30f, e1 = -1e30f, e2 = -1e30f, e3 = -1e30f;
    bool v0 = lane < deg;
    if (v0){
        src0 = colsrc[start + lane];
        float4 as = *(const float4*)(asrc + (size_t)src0 * 4);
        e0 = leaky(as.x + ad.x); e1 = leaky(as.y + ad.y);
        e2 = leaky(as.z + ad.z); e3 = leaky(as.w + ad.w);
    }
    float m0 = e0, m1 = e1, m2 = e2, m3 = e3;
    float t0 = v0 ? 1.f : 0.f, t1 = t0, t2 = t0, t3 = t0;
    for (int i = start + 64 + lane; i < end; i += 64){
        int s = colsrc[i];
        float4 as = *(const float4*)(asrc + (size_t)s * 4);
        float e, nm;
        e = leaky(as.x + ad.x); nm = fmaxf(m0, e); t0 = t0 * __expf(m0 - nm) + __expf(e - nm); m0 = nm;
        e = leaky(as.y + ad.y); nm = fmaxf(m1, e); t1 = t1 * __expf(m1 - nm) + __expf(e - nm); m1 = nm;
        e = leaky(as.z + ad.z); nm = fmaxf(m2, e); t2 = t2 * __expf(m2 - nm) + __expf(e - nm); m2 = nm;
        e = leaky(as.w + ad.w); nm = fmaxf(m3, e); t3 = t3 * __expf(m3 - nm) + __expf(e - nm); m3 = nm;
    }
    #pragma unroll
    for (int off = 1; off < 64; off <<= 1){
        float om, os, nm;
        om = __shfl_xor(m0, off); os = __shfl_xor(t0, off);
        nm = fmaxf(m0, om); t0 = t0 * __expf(m0 - nm) + os * __expf(om - nm); m0 = nm;
        om = __shfl_xor(m1, off); os = __shfl_xor(t1, off);
        nm = fmaxf(m1, om); t1 = t1 * __expf(m1 - nm) + os * __expf(om - nm); m1 = nm;
        om = __shfl_xor(m2, off); os = __shfl_xor(t2, off);
        nm = fmaxf(m2, om); t2 = t2 * __expf(m2 - nm) + os * __expf(om - nm); m2 = nm;
        om = __shfl_xor(m3, off); os = __shfl_xor(t3, off);
        nm = fmaxf(m3, om); t3 = t3 * __expf(m3 - nm) + os * __expf(om - nm); m3 = nm;
    }
    float i0 = 1.f / t0, i1 = 1.f / t1, i2 = 1.f / t2, i3 = 1.f / t3;

    float accA = 0.f, accB = 0.f;
    const int boff = lane * 8;
    {
        float w0 = __expf(e0 - m0) * i0;
        float w1 = __expf(e1 - m1) * i1;
        float w2 = __expf(e2 - m2) * i2;
        float w3 = __expf(e3 - m3) * i3;
        int off = v0 ? src0 * (HC * 2) : 0;
        s_off[wv][lane] = off;
        half2_t p01 = __builtin_amdgcn_cvt_pkrtz(w0, w1);
        half2_t p23 = __builtin_amdgcn_cvt_pkrtz(w2, w3);
        s_w[wv][lane] = (uint2){ __builtin_bit_cast(unsigned, p01),
                                 __builtin_bit_cast(unsigned, p23) };
        int cnt = deg < 64 ? deg : 64;
        edge_sweep(&s_off[wv][0], &s_w[wv][0], h, boff, cnt, accA, accB);
    }
    for (int base = start + 64; base < end; base += 64){
        int cnt = end - base; if (cnt > 64) cnt = 64;
        float w0 = 0.f, w1 = 0.f, w2 = 0.f, w3 = 0.f; int off = 0;
        if (lane < cnt){
            int s = colsrc[base + lane];
            float4 as = *(const float4*)(asrc + (size_t)s * 4);
            w0 = __expf(leaky(as.x + ad.x) - m0) * i0;
            w1 = __expf(leaky(as.y + ad.y) - m1) * i1;
            w2 = __expf(leaky(as.z + ad.z) - m2) * i2;
            w3 = __expf(leaky(as.w + ad.w) - m3) * i3;
            off = s * (HC * 2);
        }
        s_off[wv][lane] = off;
        half2_t p01 = __builtin_amdgcn_cvt_pkrtz(w0, w1);
        half2_t p23 = __builtin_amdgcn_cvt_pkrtz(w2, w3);
        s_w[wv][lane] = (uint2){ __builtin_bit_cast(unsigned, p01),
                                 __builtin_bit_cast(unsigned, p23) };
        edge_sweep(&s_off[wv][0], &s_w[wv][0], h, boff, cnt, accA, accB);
    }

    float o = (accA + accB) * 0.25f + bias[lane];
    hout[(size_t)n * CH + lane] = (o > 0.f) ? o : expm1f(o);
}

// ---------------- scorer: MFMA (bf16x3) for hmid@Ws1, fp32 epilogue ----------------

__global__ __launch_bounds__(256) void scorer_mfma_kernel(
    const float* __restrict__ h2, const short* __restrict__ s1hi, const short* __restrict__ s1lo,
    const float* __restrict__ d1p, const float* __restrict__ Ws2, const float* __restrict__ bs2,
    float* __restrict__ out, int N)
{
    constexpr int XP = 68, WP = 72;
    __shared__ float xl[64 * XP];
    __shared__ short whi[64 * WP];
    __shared__ short wlo[64 * WP];
    const int tid = threadIdx.x;
    const int n0 = blockIdx.x * 64;

    for (int t = tid; t < 64 * 16; t += 256) {
        int row = t >> 4, c4 = (t & 15) * 4;
        int n = n0 + row;
        float4 v = make_float4(0.f, 0.f, 0.f, 0.f);
        if (n < N) v = *(const float4*)(h2 + (size_t)n * 64 + c4);
        *(float4*)(xl + row * XP + c4) = v;
    }
    {
        const short8* ghi = (const short8*)s1hi;
        const short8* glo = (const short8*)s1lo;
        short8* lhi = (short8*)whi;
        short8* llo = (short8*)wlo;
        for (int t = tid; t < 64 * WP / 8; t += 256){ lhi[t] = ghi[t]; llo[t] = glo[t]; }
    }
    __syncthreads();

    const int wv = tid >> 6, lane = tid & 63;
    const int quad = lane >> 4, ln = lane & 15;
    const int myrow = wv * 16 + ln;

    f32x4 acc[4];
    #pragma unroll
    for (int i = 0; i < 4; ++i) acc[i] = (f32x4){0.f, 0.f, 0.f, 0.f};

    #pragma unroll
    for (int ks = 0; ks < 2; ++ks) {
        const int k0 = ks * 32 + quad * 8;
        const float* ap = xl + myrow * XP + k0;
        float4 f0 = *(const float4*)ap;
        float4 f1 = *(const float4*)(ap + 4);
        float fa[8] = {f0.x, f0.y, f0.z, f0.w, f1.x, f1.y, f1.z, f1.w};
        short8 ahi, alo;
        #pragma unroll
        for (int e = 0; e < 8; ++e) {
            short hi = bf16_rne(fa[e]);
            ahi[e] = hi;
            alo[e] = bf16_rne(fa[e] - bf16_to_f(hi));
        }
        #pragma unroll
        for (int nt = 0; nt < 4; ++nt) {
            short8 bhi = *(const short8*)(whi + (nt * 16 + ln) * WP + k0);
            short8 blo = *(const short8*)(wlo + (nt * 16 + ln) * WP + k0);
            acc[nt] = __builtin_amdgcn_mfma_f32_16x16x32_bf16(ahi, bhi, acc[nt], 0, 0, 0);
            acc[nt] = __builtin_amdgcn_mfma_f32_16x16x32_bf16(alo, bhi, acc[nt], 0, 0, 0);
            acc[nt] = __builtin_amdgcn_mfma_f32_16x16x32_bf16(ahi, blo, acc[nt], 0, 0, 0);
        }
    }

    float d1v[4], w2v[4];
    #pragma unroll
    for (int nt = 0; nt < 4; ++nt){
        d1v[nt] = d1p[nt * 16 + ln];
        w2v[nt] = Ws2[nt * 16 + ln];
    }
    float b2 = bs2[0];
    #pragma unroll
    for (int r = 0; r < 4; ++r){
        float t = 0.f;
        #pragma unroll
        for (int nt = 0; nt < 4; ++nt)
            t = fmaf(fmaxf(acc[nt][r] + d1v[nt], 0.f), w2v[nt], t);
        #pragma unroll
        for (int off = 1; off < 16; off <<= 1) t += __shfl_xor(t, off);
        if (ln == 0){
            int n = n0 + wv * 16 + quad * 4 + r;
            if (n < N) out[n] = t + b2;
        }
    }
}

// ---------------- launch ----------------

extern "C" void kernel_launch(void* const* d_in, const int* in_sizes, int n_in,
                              void* d_out, int out_size, void* d_ws, size_t ws_size,
                              hipStream_t stream)
{
    const float* x    = (const float*)d_in[0];
    const int*   ei   = (const int*)  d_in[1];
    const float* donor= (const float*)d_in[2];
    const float* W1   = (const float*)d_in[3];
    const float* as1  = (const float*)d_in[4];
    const float* ad1  = (const float*)d_in[5];
    const float* b1   = (const float*)d_in[6];
    const float* W2   = (const float*)d_in[7];
    const float* as2  = (const float*)d_in[8];
    const float* ad2  = (const float*)d_in[9];
    const float* b2   = (const float*)d_in[10];
    const float* Ws1  = (const float*)d_in[11];
    const float* bs1  = (const float*)d_in[12];
    const float* Ws2  = (const float*)d_in[13];
    const float* bs2  = (const float*)d_in[14];

    const int N  = in_sizes[0] / 27;
    const int E  = in_sizes[1] / 2;
    const int ET = E + N;

    char* ws = (char*)d_ws;
    auto alloc = [&](size_t bytes) -> void* {
        void* p = (void*)ws;
        ws += (bytes + 255) / 256 * 256;
        return p;
    };
    int*    rowptr = (int*)   alloc((size_t)(N + 1) * 4);
    int*    deg    = (int*)   alloc((size_t)N * 4);
    int*    cursor = (int*)   alloc((size_t)N * 4);
    int*    colsrc = (int*)   alloc((size_t)ET * 4);
    __half* hbig   = (__half*)alloc((size_t)N * HC * 2);
    float*  asrc   = (float*) alloc((size_t)N * 4 * 4);
    float*  adst   = (float*) alloc((size_t)N * 4 * 4);
    float*  hmid   = (float*) alloc((size_t)N * CH * 4);
    const int SB = (N + SCAN_TILE - 1) / SCAN_TILE;
    int*    bsum   = (int*)   alloc((size_t)SB * 4);
    short*  w1hi   = (short*) alloc(256 * 40 * 2);
    short*  w1lo   = (short*) alloc(256 * 40 * 2);
    short*  w2hi   = (short*) alloc(256 * 72 * 2);
    short*  w2lo   = (short*) alloc(256 * 72 * 2);
    short*  s1hi   = (short*) alloc(64 * 72 * 2);
    short*  s1lo   = (short*) alloc(64 * 72 * 2);
    float*  d1p    = (float*) alloc(64 * 4);

    const int nblk = (N + 63) / 64;
    const int cblk = (ET + 255) / 256;

    // 1. prep: zero deg + weight splits + d1
    prep_kernel<<<256, 256, 0, stream>>>(W1, W2, Ws1, bs1, donor,
        deg, w1hi, w1lo, w2hi, w2lo, s1hi, s1lo, d1p, N);
    // 2. layer1 transform fused with edge count
    transform1_count_kernel<<<nblk + cblk, 256, 0, stream>>>(
        x, w1hi, w1lo, as1, ad1, hbig, asrc, adst, N, nblk, ei, E, deg);
    // 3-4. scan
    blocksum_kernel<<<SB, 256, 0, stream>>>(deg, N, bsum);
    scan_write_kernel<<<SB, 256, 0, stream>>>(deg, bsum, N, ET, rowptr, cursor);
    // 5. scatter
    scatter_kernel<<<cblk, 256, 0, stream>>>(ei, E, N, cursor, colsrc);
    // 6. aggregate layer1
    aggregate_kernel<<<(N + 3) / 4, 256, 0, stream>>>(
        rowptr, colsrc, hbig, asrc, adst, b1, hmid, N);
    // 7. layer2 transform
    transform2_kernel<<<dim3(nblk, 2), 256, 0, stream>>>(
        hmid, w2hi, w2lo, as2, ad2, hbig, asrc, adst, N);
    // 8. aggregate layer2
    aggregate_kernel<<<(N + 3) / 4, 256, 0, stream>>>(
        rowptr, colsrc, hbig, asrc, adst, b2, hmid, N);
    // 9. scorer
    scorer_mfma_kernel<<<nblk, 256, 0, stream>>>(
        hmid, s1hi, s1lo, d1p, Ws2, bs2, (float*)d_out, N);
}